// Round 6
// baseline (136.000 us; speedup 1.0000x reference)
//
#include <hip/hip_runtime.h>
#include <math.h>

// Problem constants
#define HH 256
#define SS 32768
#define BB 8
#define NEGV (-10000000000.0f)

// Output layout (floats): result(2048) | h_new(2048) | evidence(8) | attn(262144) | new_mask(262144)
#define OUT_RESULT 0
#define OUT_HNEW   2048
#define OUT_EV     4096
#define OUT_ATT    4104
#define OUT_MASK   266248

// Workspace layout (floats)
#define WS_HNEW  0
#define WS_Q1    2048
#define WS_C1    4096              // 8 floats
#define WS_GATES 4112              // 1536 rows x 8 batches (transposed gates)
#define WS_PART  (4112 + 12288)    // 16400
#define PART_STRIDE 264            // ctx[256] + m,l,bestv,bestidx (+pad)
#define CHUNKS_PER_B 128           // 128 chunks * 256 s = 32768
#define S_PER_BLOCK 256
#define S_PER_WAVE 64

__device__ __forceinline__ float rl(float x, int srclane) {
    return __int_as_float(__builtin_amdgcn_readlane(__float_as_int(x), srclane));
}
__device__ __forceinline__ float dot4(float4 a, float4 b) {
    return a.x * b.x + a.y * b.y + a.z * b.z + a.w * b.w;
}
// merged 4-way wave reduction: 7 shuffles; lanes with lane%4==i hold full sum of p_i
__device__ __forceinline__ float merge4(float p0, float p1, float p2, float p3, int lane) {
    const bool lb0 = lane & 1;
    float r01 = (lb0 ? p1 : p0) + __shfl_xor(lb0 ? p0 : p1, 1);
    float r23 = (lb0 ? p3 : p2) + __shfl_xor(lb0 ? p2 : p3, 1);
    const bool lb1 = lane & 2;
    float r = (lb1 ? r23 : r01) + __shfl_xor(lb1 ? r01 : r23, 2);
    r += __shfl_xor(r, 4);
    r += __shfl_xor(r, 8);
    r += __shfl_xor(r, 16);
    r += __shfl_xor(r, 32);
    return r;
}

// ---------------- Kernel A1: row-parallel gates GEMV (192 blocks x 8 rows) ----------------
__global__ __launch_bounds__(256) void gates_gemv(
    const float* __restrict__ dec_in, const float* __restrict__ last_hidden,
    const float* __restrict__ W_ih, const float* __restrict__ W_hh,
    float* __restrict__ ws)
{
    const int t = threadIdx.x;
    const int w = t >> 6, lane = t & 63;
    const bool ih = (blockIdx.x < 96);

    __shared__ __align__(16) float4 s4[BB][HH / 4];
    {
        const float* src = ih ? dec_in : last_hidden;
        float* sf = (float*)s4;
        #pragma unroll
        for (int i = 0; i < 8; ++i)
            sf[i * 256 + t] = src[i * 256 + t];
    }
    __syncthreads();

    const int local = ih ? blockIdx.x : (blockIdx.x - 96);
    const int rbase = local * 8 + w * 2;
    const float* W = ih ? W_ih : W_hh;

    #pragma unroll
    for (int rr = 0; rr < 2; ++rr) {
        const int r = rbase + rr;
        const float4 rv = ((const float4*)(W + (size_t)r * HH))[lane];

        float p[8];
        #pragma unroll
        for (int b = 0; b < 8; ++b)
            p[b] = dot4(rv, s4[b][lane]);

        // merged 8-way butterfly: 10 shuffles; lane&7==b holds full dot for batch b
        const bool l1 = lane & 1;
        float q01 = (l1 ? p[1] : p[0]) + __shfl_xor(l1 ? p[0] : p[1], 1);
        float q23 = (l1 ? p[3] : p[2]) + __shfl_xor(l1 ? p[2] : p[3], 1);
        float q45 = (l1 ? p[5] : p[4]) + __shfl_xor(l1 ? p[4] : p[5], 1);
        float q67 = (l1 ? p[7] : p[6]) + __shfl_xor(l1 ? p[6] : p[7], 1);
        const bool l2 = lane & 2;
        float r03 = (l2 ? q23 : q01) + __shfl_xor(l2 ? q01 : q23, 2);
        float r47 = (l2 ? q67 : q45) + __shfl_xor(l2 ? q45 : q67, 2);
        const bool l4 = lane & 4;
        float s = (l4 ? r47 : r03) + __shfl_xor(l4 ? r03 : r47, 4);
        s += __shfl_xor(s, 8);
        s += __shfl_xor(s, 16);
        s += __shfl_xor(s, 32);

        if (lane < 8)
            ws[WS_GATES + (size_t)(ih ? r : 768 + r) * 8 + lane] = s;
    }
}

// ---------------- Kernel A2: GRU combine + q1/c1 (64 blocks = 8 batch x 8 colgroups) ----
__global__ __launch_bounds__(256) void gru_q1(
    const float* __restrict__ last_hidden,
    const float* __restrict__ W1, const float* __restrict__ b1,
    const float* __restrict__ b_ih, const float* __restrict__ b_hh,
    float* __restrict__ ws, float* __restrict__ out)
{
    const int blk = blockIdx.x;
    const int b = blk >> 3;        // batch
    const int cg = blk & 7;        // k-column group [cg*32, cg*32+32)
    const int t = threadIdx.x;
    __shared__ float hn[HH];
    __shared__ float qpart[8][32];
    __shared__ float red[256];

    const float* gT = ws + WS_GATES;
    float gi0 = gT[(size_t)(t)         * 8 + b] + b_ih[t];
    float gi1 = gT[(size_t)(t + HH)    * 8 + b] + b_ih[t + HH];
    float gi2 = gT[(size_t)(t + 2*HH)  * 8 + b] + b_ih[t + 2*HH];
    float gh0 = gT[(size_t)(768 + t)        * 8 + b] + b_hh[t];
    float gh1 = gT[(size_t)(768 + t + HH)   * 8 + b] + b_hh[t + HH];
    float gh2 = gT[(size_t)(768 + t + 2*HH) * 8 + b] + b_hh[t + 2*HH];

    const float hprev = last_hidden[b * HH + t];
    float r = 1.0f / (1.0f + expf(-(gi0 + gh0)));
    float z = 1.0f / (1.0f + expf(-(gi1 + gh1)));
    float n = tanhf(gi2 + r * gh2);
    float hnew = (1.0f - z) * n + z * hprev;

    hn[t] = hnew;
    red[t] = hnew * b1[t];
    if (cg == 0) {
        ws[WS_HNEW + b * HH + t] = hnew;
        out[OUT_HNEW + b * HH + t] = hnew;
    }
    __syncthreads();

    // q1 partial: thread (kl, hg) sums 32 h values for column k
    const int kl = t & 31, hg = t >> 5;
    const int k = cg * 32 + kl;
    float acc = 0.0f;
    #pragma unroll 8
    for (int j = 0; j < 32; ++j) {
        int h = hg * 32 + j;
        acc += hn[h] * W1[(size_t)h * HH + k];
    }
    qpart[hg][kl] = acc;
    __syncthreads();
    if (t < 32) {
        float s = 0.0f;
        #pragma unroll
        for (int j = 0; j < 8; ++j) s += qpart[j][t];
        ws[WS_Q1 + b * HH + cg * 32 + t] = s;
    }

    if (cg == 0) {   // block-uniform branch: barriers legal
        for (int s = 128; s > 0; s >>= 1) {
            if (t < s) red[t] += red[t + s];
            __syncthreads();
        }
        if (t == 0) ws[WS_C1 + b] = red[0];
    }
}

// ---------------- Kernel B: streaming scores + online softmax context ----------------
// Depth-2 double-buffered prefetch, fully unrolled 16-group loop.
__global__ __launch_bounds__(256, 4) void attn_main(
    const float* __restrict__ eo, const float* __restrict__ mask,
    const float* __restrict__ gum, float* __restrict__ ws,
    float* __restrict__ out)
{
    const int blk = blockIdx.x;
    const int b = blk >> 7;            // CHUNKS_PER_B = 128
    const int chunk = blk & 127;
    const int t = threadIdx.x;
    const int w = t >> 6, lane = t & 63;
    const int sbase = chunk * S_PER_BLOCK;
    const int swave = sbase + w * S_PER_WAVE;

    // mask pass-through copy (evidence slot overwritten by finalize)
    out[OUT_MASK + (size_t)b * SS + sbase + t] = mask[(size_t)b * SS + sbase + t];

    const float4 q = ((const float4*)(ws + WS_Q1 + b * HH))[lane];
    const float c1 = ws[WS_C1 + b];

    const float mk = mask[(size_t)b * SS + swave + lane];
    const float uu = gum[(size_t)b * SS + swave + lane];
    const float gl = -logf(-logf(uu));
    const float mg = mk + gl;   // per-lane (lane = row within wave tile)

    const float4* base = (const float4*)(eo + ((size_t)b * SS + swave) * HH);

    float m = -INFINITY, l = 0.0f;
    float bv = -INFINITY; int bi = 0;
    float4 ctx = {0.f, 0.f, 0.f, 0.f};
    float my_t = 0.0f;

    // 2-deep register double buffer: buf[0] holds even groups, buf[1] odd
    float4 buf[2][4];
    #pragma unroll
    for (int j = 0; j < 4; ++j) buf[0][j] = base[j * 64 + lane];
    #pragma unroll
    for (int j = 0; j < 4; ++j) buf[1][j] = base[(4 + j) * 64 + lane];

    #pragma unroll
    for (int g = 0; g < 16; ++g) {
        const int cur = g & 1;                  // compile-time after unroll
        float4 n0, n1, n2, n3;
        const bool pf = (g + 2 < 16);
        if (pf) {
            const float4* nb = base + (size_t)(g + 2) * 4 * 64;
            n0 = nb[0 * 64 + lane];
            n1 = nb[1 * 64 + lane];
            n2 = nb[2 * 64 + lane];
            n3 = nb[3 * 64 + lane];
        }
        const float4 v0 = buf[cur][0], v1 = buf[cur][1];
        const float4 v2 = buf[cur][2], v3 = buf[cur][3];

        float r = merge4(dot4(v0, q), dot4(v1, q), dot4(v2, q), dot4(v3, q), lane);

        float tg0, tg1, tg2, tg3;
        #pragma unroll
        for (int i = 0; i < 4; ++i) {
            float u = rl(r, i) + c1;              // uniform: dot + c1
            if (lane == 4 * g + i) my_t = u + mk; // attn_outputs for own row
            float tgi = u + rl(mg, 4 * g + i);    // + mask + gumbel
            if (tgi > bv) { bv = tgi; bi = swave + 4 * g + i; }  // first-max tie-break
            if (i == 0) tg0 = tgi; else if (i == 1) tg1 = tgi;
            else if (i == 2) tg2 = tgi; else tg3 = tgi;
        }

        float gmax = fmaxf(fmaxf(tg0, tg1), fmaxf(tg2, tg3));
        if (gmax > m) {                           // wave-uniform
            float sc = __expf(m - gmax);
            l *= sc; ctx.x *= sc; ctx.y *= sc; ctx.z *= sc; ctx.w *= sc;
            m = gmax;
        }
        float w0 = __expf(tg0 - m), w1 = __expf(tg1 - m);
        float w2 = __expf(tg2 - m), w3 = __expf(tg3 - m);
        l += (w0 + w1) + (w2 + w3);
        ctx.x += w0*v0.x + w1*v1.x + w2*v2.x + w3*v3.x;
        ctx.y += w0*v0.y + w1*v1.y + w2*v2.y + w3*v3.y;
        ctx.z += w0*v0.z + w1*v1.z + w2*v2.z + w3*v3.z;
        ctx.w += w0*v0.w + w1*v1.w + w2*v2.w + w3*v3.w;

        if (pf) {
            buf[cur][0] = n0; buf[cur][1] = n1;
            buf[cur][2] = n2; buf[cur][3] = n3;
        }
    }

    out[OUT_ATT + (size_t)b * SS + swave + lane] = my_t;

    // combine 4 waves -> 1 block partial
    __shared__ float pm[4], pl[4], pbv[4];
    __shared__ int pbi[4];
    __shared__ __align__(16) float pctx[4][HH];
    ((float4*)pctx[w])[lane] = ctx;
    if (lane == 0) { pm[w] = m; pl[w] = l; pbv[w] = bv; pbi[w] = bi; }
    __syncthreads();

    float M4 = fmaxf(fmaxf(pm[0], pm[1]), fmaxf(pm[2], pm[3]));
    float e0 = __expf(pm[0] - M4), e1 = __expf(pm[1] - M4);
    float e2 = __expf(pm[2] - M4), e3 = __expf(pm[3] - M4);
    float Lc = pl[0]*e0 + pl[1]*e1 + pl[2]*e2 + pl[3]*e3;
    float cc = pctx[0][t]*e0 + pctx[1][t]*e1 + pctx[2][t]*e2 + pctx[3][t]*e3;

    float* part = ws + WS_PART + (size_t)blk * PART_STRIDE;
    part[t] = cc;
    if (t == 0) {
        float bbv = pbv[0]; int bbi = pbi[0];
        #pragma unroll
        for (int i = 1; i < 4; ++i)
            if (pbv[i] > bbv || (pbv[i] == bbv && pbi[i] < bbi)) { bbv = pbv[i]; bbi = pbi[i]; }
        part[256] = M4; part[257] = Lc; part[258] = bbv; part[259] = (float)bbi;
    }
}

// ---------------- Kernel C: combine partials + projections + scatter ----------------
__global__ __launch_bounds__(256) void finalize(
    const float* __restrict__ W2, const float* __restrict__ b2,
    const float* __restrict__ W3, const float* __restrict__ b3,
    float* __restrict__ ws, float* __restrict__ out)
{
    const int b = blockIdx.x, t = threadIdx.x;
    const int w = t >> 6, lane = t & 63;
    __shared__ float marr[128], mred[128], lred[128], e_sh[128], bvred[128];
    __shared__ int bired[128];
    __shared__ __align__(16) float cat[2 * HH];   // [ctx_raw | hn]
    __shared__ __align__(16) float cat2[2 * HH];  // [context | hn]

    const float* parts = ws + WS_PART + (size_t)b * CHUNKS_PER_B * PART_STRIDE;
    float lraw = 0.0f;
    if (t < 128) {
        const float* p = parts + (size_t)t * PART_STRIDE + 256;
        float mv = p[0]; lraw = p[1];
        marr[t] = mv; mred[t] = mv;
        bvred[t] = p[2]; bired[t] = (int)p[3];
    }
    __syncthreads();
    for (int s = 64; s > 0; s >>= 1) {
        if (t < s) {
            mred[t] = fmaxf(mred[t], mred[t + s]);
            if (bvred[t + s] > bvred[t] ||
                (bvred[t + s] == bvred[t] && bired[t + s] < bired[t])) {
                bvred[t] = bvred[t + s]; bired[t] = bired[t + s];
            }
        }
        __syncthreads();
    }
    const float M = mred[0];
    if (t < 128) {
        float e = __expf(marr[t] - M);
        e_sh[t] = e;
        lred[t] = lraw * e;
    }
    __syncthreads();
    for (int s = 64; s > 0; s >>= 1) {
        if (t < s) lred[t] += lred[t + s];
        __syncthreads();
    }
    const float L = lred[0];
    const int best = bired[0];

    // ctx_raw[t] = (sum_c part_c[t] * e_c) / L
    float acc = 0.0f;
    #pragma unroll 16
    for (int c = 0; c < CHUNKS_PER_B; ++c)
        acc += parts[(size_t)c * PART_STRIDE + t] * e_sh[c];
    const float hnv = ws[WS_HNEW + b * HH + t];
    cat[t] = acc / L;
    cat[HH + t] = hnv;
    cat2[HH + t] = hnv;
    __syncthreads();

    // context = W2 . ctx_raw + b2 : wave-per-4-rows, coalesced row loads
    {
        const float4* v4 = (const float4*)cat;   // 64 float4 of ctx_raw
        const float4 vv = v4[lane];
        #pragma unroll 4
        for (int grp = 0; grp < 16; ++grp) {
            const int rbase = w * 64 + grp * 4;
            float4 w0 = ((const float4*)(W2 + (size_t)(rbase + 0) * HH))[lane];
            float4 w1 = ((const float4*)(W2 + (size_t)(rbase + 1) * HH))[lane];
            float4 w2v = ((const float4*)(W2 + (size_t)(rbase + 2) * HH))[lane];
            float4 w3v = ((const float4*)(W2 + (size_t)(rbase + 3) * HH))[lane];
            float r = merge4(dot4(w0, vv), dot4(w1, vv), dot4(w2v, vv), dot4(w3v, vv), lane);
            if (lane < 4)
                cat2[rbase + lane] = r + b2[rbase + lane];
        }
    }
    __syncthreads();

    // result = W3 . [context, hn] + b3 : rows are 512 wide
    {
        const float4* c4 = (const float4*)cat2;  // 128 float4
        const float4 clo = c4[lane], chi = c4[lane + 64];
        #pragma unroll 4
        for (int grp = 0; grp < 16; ++grp) {
            const int rbase = w * 64 + grp * 4;
            float p[4];
            #pragma unroll
            for (int i = 0; i < 4; ++i) {
                const float4* row = (const float4*)(W3 + (size_t)(rbase + i) * 2 * HH);
                p[i] = dot4(row[lane], clo) + dot4(row[lane + 64], chi);
            }
            float r = merge4(p[0], p[1], p[2], p[3], lane);
            if (lane < 4)
                out[OUT_RESULT + b * HH + rbase + lane] = r + b3[rbase + lane];
        }
    }

    if (t == 0) {
        out[OUT_EV + b] = (float)best;
        out[OUT_MASK + (size_t)b * SS + best] = NEGV;
    }
}

extern "C" void kernel_launch(void* const* d_in, const int* in_sizes, int n_in,
                              void* d_out, int out_size, void* d_ws, size_t ws_size,
                              hipStream_t stream) {
    const float* last_hidden = (const float*)d_in[0];
    const float* dec         = (const float*)d_in[1];
    const float* eo          = (const float*)d_in[2];
    const float* mask        = (const float*)d_in[3];
    const float* gum         = (const float*)d_in[4];
    const float* W1          = (const float*)d_in[5];
    const float* b1          = (const float*)d_in[6];
    const float* W2          = (const float*)d_in[7];
    const float* b2          = (const float*)d_in[8];
    const float* W3          = (const float*)d_in[9];
    const float* b3          = (const float*)d_in[10];
    const float* W_ih        = (const float*)d_in[11];
    const float* W_hh        = (const float*)d_in[12];
    const float* b_ih        = (const float*)d_in[13];
    const float* b_hh        = (const float*)d_in[14];
    float* out = (float*)d_out;
    float* ws  = (float*)d_ws;

    hipLaunchKernelGGL(gates_gemv, dim3(192), dim3(256), 0, stream,
                       dec, last_hidden, W_ih, W_hh, ws);
    hipLaunchKernelGGL(gru_q1, dim3(64), dim3(256), 0, stream,
                       last_hidden, W1, b1, b_ih, b_hh, ws, out);
    hipLaunchKernelGGL(attn_main, dim3(BB * CHUNKS_PER_B), dim3(256), 0, stream,
                       eo, mask, gum, ws, out);
    hipLaunchKernelGGL(finalize, dim3(BB), dim3(256), 0, stream,
                       W2, b2, W3, b3, ws, out);
}

// Round 7
// 116.853 us; speedup vs baseline: 1.1639x; 1.1639x over previous
//
#include <hip/hip_runtime.h>
#include <math.h>

// Problem constants
#define HH 256
#define SS 32768
#define BB 8
#define NEGV (-10000000000.0f)

// Output layout (floats): result(2048) | h_new(2048) | evidence(8) | attn(262144) | new_mask(262144)
#define OUT_RESULT 0
#define OUT_HNEW   2048
#define OUT_EV     4096
#define OUT_ATT    4104
#define OUT_MASK   266248

// Workspace layout (floats)
#define WS_HNEW  0
#define WS_Q1    2048
#define WS_C1    4096              // 8 floats
#define WS_GATES 4112              // 1536 rows x 8 batches (transposed gates)
#define WS_PART  (4112 + 12288)    // 16400
#define PART_STRIDE 264            // ctx[256] + m,l,bestv,bestidx (+pad)
#define CHUNKS_PER_B 256           // 256 chunks * 128 s = 32768
#define S_PER_BLOCK 128
#define S_PER_WAVE 32

__device__ __forceinline__ float rl(float x, int srclane) {
    return __int_as_float(__builtin_amdgcn_readlane(__float_as_int(x), srclane));
}
__device__ __forceinline__ float dot4(float4 a, float4 b) {
    return a.x * b.x + a.y * b.y + a.z * b.z + a.w * b.w;
}
// merged 4-way wave reduction: 7 shuffles; lanes with lane%4==i hold full sum of p_i
__device__ __forceinline__ float merge4(float p0, float p1, float p2, float p3, int lane) {
    const bool lb0 = lane & 1;
    float r01 = (lb0 ? p1 : p0) + __shfl_xor(lb0 ? p0 : p1, 1);
    float r23 = (lb0 ? p3 : p2) + __shfl_xor(lb0 ? p2 : p3, 1);
    const bool lb1 = lane & 2;
    float r = (lb1 ? r23 : r01) + __shfl_xor(lb1 ? r01 : r23, 2);
    r += __shfl_xor(r, 4);
    r += __shfl_xor(r, 8);
    r += __shfl_xor(r, 16);
    r += __shfl_xor(r, 32);
    return r;
}
// merged 8-way wave reduction: 10 shuffles; lanes with lane%8==i hold full sum of p_i
__device__ __forceinline__ float merge8(const float* p, int lane) {
    const bool l1 = lane & 1;
    float q01 = (l1 ? p[1] : p[0]) + __shfl_xor(l1 ? p[0] : p[1], 1);
    float q23 = (l1 ? p[3] : p[2]) + __shfl_xor(l1 ? p[2] : p[3], 1);
    float q45 = (l1 ? p[5] : p[4]) + __shfl_xor(l1 ? p[4] : p[5], 1);
    float q67 = (l1 ? p[7] : p[6]) + __shfl_xor(l1 ? p[6] : p[7], 1);
    const bool l2 = lane & 2;
    float r03 = (l2 ? q23 : q01) + __shfl_xor(l2 ? q01 : q23, 2);
    float r47 = (l2 ? q67 : q45) + __shfl_xor(l2 ? q45 : q67, 2);
    const bool l4 = lane & 4;
    float s = (l4 ? r47 : r03) + __shfl_xor(l4 ? r03 : r47, 4);
    s += __shfl_xor(s, 8);
    s += __shfl_xor(s, 16);
    s += __shfl_xor(s, 32);
    return s;
}

// ---------------- Kernel A1: row-parallel gates GEMV (192 blocks x 8 rows) ----------------
__global__ __launch_bounds__(256) void gates_gemv(
    const float* __restrict__ dec_in, const float* __restrict__ last_hidden,
    const float* __restrict__ W_ih, const float* __restrict__ W_hh,
    float* __restrict__ ws)
{
    const int t = threadIdx.x;
    const int w = t >> 6, lane = t & 63;
    const bool ih = (blockIdx.x < 96);

    __shared__ __align__(16) float4 s4[BB][HH / 4];
    {
        const float* src = ih ? dec_in : last_hidden;
        float* sf = (float*)s4;
        #pragma unroll
        for (int i = 0; i < 8; ++i)
            sf[i * 256 + t] = src[i * 256 + t];
    }
    __syncthreads();

    const int local = ih ? blockIdx.x : (blockIdx.x - 96);
    const int rbase = local * 8 + w * 2;
    const float* W = ih ? W_ih : W_hh;

    #pragma unroll
    for (int rr = 0; rr < 2; ++rr) {
        const int r = rbase + rr;
        const float4 rv = ((const float4*)(W + (size_t)r * HH))[lane];

        float p[8];
        #pragma unroll
        for (int b = 0; b < 8; ++b)
            p[b] = dot4(rv, s4[b][lane]);

        float s = merge8(p, lane);

        if (lane < 8)
            ws[WS_GATES + (size_t)(ih ? r : 768 + r) * 8 + lane] = s;
    }
}

// ---------------- Kernel A2: GRU combine + q1/c1 (64 blocks = 8 batch x 8 colgroups) ----
__global__ __launch_bounds__(256) void gru_q1(
    const float* __restrict__ last_hidden,
    const float* __restrict__ W1, const float* __restrict__ b1,
    const float* __restrict__ b_ih, const float* __restrict__ b_hh,
    float* __restrict__ ws, float* __restrict__ out)
{
    const int blk = blockIdx.x;
    const int b = blk >> 3;        // batch
    const int cg = blk & 7;        // k-column group [cg*32, cg*32+32)
    const int t = threadIdx.x;
    __shared__ float hn[HH];
    __shared__ float qpart[8][32];
    __shared__ float red[256];

    const float* gT = ws + WS_GATES;
    float gi0 = gT[(size_t)(t)         * 8 + b] + b_ih[t];
    float gi1 = gT[(size_t)(t + HH)    * 8 + b] + b_ih[t + HH];
    float gi2 = gT[(size_t)(t + 2*HH)  * 8 + b] + b_ih[t + 2*HH];
    float gh0 = gT[(size_t)(768 + t)        * 8 + b] + b_hh[t];
    float gh1 = gT[(size_t)(768 + t + HH)   * 8 + b] + b_hh[t + HH];
    float gh2 = gT[(size_t)(768 + t + 2*HH) * 8 + b] + b_hh[t + 2*HH];

    const float hprev = last_hidden[b * HH + t];
    float r = 1.0f / (1.0f + expf(-(gi0 + gh0)));
    float z = 1.0f / (1.0f + expf(-(gi1 + gh1)));
    float n = tanhf(gi2 + r * gh2);
    float hnew = (1.0f - z) * n + z * hprev;

    hn[t] = hnew;
    red[t] = hnew * b1[t];
    if (cg == 0) {
        ws[WS_HNEW + b * HH + t] = hnew;
        out[OUT_HNEW + b * HH + t] = hnew;
    }
    __syncthreads();

    // q1 partial: thread (kl, hg) sums 32 h values for column k
    const int kl = t & 31, hg = t >> 5;
    const int k = cg * 32 + kl;
    float acc = 0.0f;
    #pragma unroll 8
    for (int j = 0; j < 32; ++j) {
        int h = hg * 32 + j;
        acc += hn[h] * W1[(size_t)h * HH + k];
    }
    qpart[hg][kl] = acc;
    __syncthreads();
    if (t < 32) {
        float s = 0.0f;
        #pragma unroll
        for (int j = 0; j < 8; ++j) s += qpart[j][t];
        ws[WS_Q1 + b * HH + cg * 32 + t] = s;
    }

    if (cg == 0) {   // block-uniform branch: barriers legal
        for (int s = 128; s > 0; s >>= 1) {
            if (t < s) red[t] += red[t + s];
            __syncthreads();
        }
        if (t == 0) ws[WS_C1 + b] = red[0];
    }
}

// ---------------- Kernel B: streaming scores + online softmax context ----------------
// 8-row groups (8KB/wave in flight, depth-1 A/B ping-pong), merge8 reduction.
__global__ __launch_bounds__(256, 4) void attn_main(
    const float* __restrict__ eo, const float* __restrict__ mask,
    const float* __restrict__ gum, float* __restrict__ ws,
    float* __restrict__ out)
{
    const int blk = blockIdx.x;
    const int b = blk >> 8;            // CHUNKS_PER_B = 256
    const int chunk = blk & 255;
    const int t = threadIdx.x;
    const int w = t >> 6, lane = t & 63;
    const int sbase = chunk * S_PER_BLOCK;
    const int swave = sbase + w * S_PER_WAVE;

    // mask pass-through copy (evidence slot overwritten by finalize)
    if (t < S_PER_BLOCK)
        out[OUT_MASK + (size_t)b * SS + sbase + t] = mask[(size_t)b * SS + sbase + t];

    const float4 q = ((const float4*)(ws + WS_Q1 + b * HH))[lane];
    const float c1 = ws[WS_C1 + b];

    float mk = 0.0f, mg = 0.0f;
    if (lane < S_PER_WAVE) {
        mk = mask[(size_t)b * SS + swave + lane];
        float uu = gum[(size_t)b * SS + swave + lane];
        mg = mk - logf(-logf(uu));
    }

    const float4* base = (const float4*)(eo + ((size_t)b * SS + swave) * HH);

    float m = -INFINITY, l = 0.0f;
    float bv = -INFINITY; int bi = 0;
    float4 ctx = {0.f, 0.f, 0.f, 0.f};
    float my_t = 0.0f;

    float4 A[8], Bv[8];

    auto loadg = [&](float4* dst, int g) {
        const float4* nb = base + (size_t)g * 8 * 64;
        #pragma unroll
        for (int j = 0; j < 8; ++j)
            dst[j] = nb[j * 64 + lane];
    };

    auto body = [&](const float4* L, int g) {
        float p[8];
        #pragma unroll
        for (int j = 0; j < 8; ++j) p[j] = dot4(L[j], q);
        float r = merge8(p, lane);

        float tg[8];
        #pragma unroll
        for (int i = 0; i < 8; ++i) {
            const int row = 8 * g + i;
            float u = rl(r, i) + c1;             // uniform: dot + c1
            if (lane == row) my_t = u + mk;      // attn_outputs for own row
            tg[i] = u + rl(mg, row);             // + mask + gumbel
            if (tg[i] > bv) { bv = tg[i]; bi = swave + row; }  // first-max tie-break
        }

        float gmax = fmaxf(fmaxf(fmaxf(tg[0], tg[1]), fmaxf(tg[2], tg[3])),
                           fmaxf(fmaxf(tg[4], tg[5]), fmaxf(tg[6], tg[7])));
        if (gmax > m) {                           // wave-uniform
            float sc = __expf(m - gmax);
            l *= sc; ctx.x *= sc; ctx.y *= sc; ctx.z *= sc; ctx.w *= sc;
            m = gmax;
        }
        float wgt[8];
        #pragma unroll
        for (int i = 0; i < 8; ++i) wgt[i] = __expf(tg[i] - m);
        #pragma unroll
        for (int i = 0; i < 8; ++i) l += wgt[i];
        #pragma unroll
        for (int i = 0; i < 8; ++i) {
            ctx.x += wgt[i] * L[i].x;
            ctx.y += wgt[i] * L[i].y;
            ctx.z += wgt[i] * L[i].z;
            ctx.w += wgt[i] * L[i].w;
        }
    };

    // 4 groups of 8 rows; A/B ping-pong, depth-1 prefetch (8KB in flight)
    loadg(A, 0);
    loadg(Bv, 1);
    body(A, 0);
    loadg(A, 2);
    body(Bv, 1);
    loadg(Bv, 3);
    body(A, 2);
    body(Bv, 3);

    if (lane < S_PER_WAVE)
        out[OUT_ATT + (size_t)b * SS + swave + lane] = my_t;

    // combine 4 waves -> 1 block partial
    __shared__ float pm[4], pl[4], pbv[4];
    __shared__ int pbi[4];
    __shared__ __align__(16) float pctx[4][HH];
    ((float4*)pctx[w])[lane] = ctx;
    if (lane == 0) { pm[w] = m; pl[w] = l; pbv[w] = bv; pbi[w] = bi; }
    __syncthreads();

    float M4 = fmaxf(fmaxf(pm[0], pm[1]), fmaxf(pm[2], pm[3]));
    float e0 = __expf(pm[0] - M4), e1 = __expf(pm[1] - M4);
    float e2 = __expf(pm[2] - M4), e3 = __expf(pm[3] - M4);
    float Lc = pl[0]*e0 + pl[1]*e1 + pl[2]*e2 + pl[3]*e3;
    float cc = pctx[0][t]*e0 + pctx[1][t]*e1 + pctx[2][t]*e2 + pctx[3][t]*e3;

    float* part = ws + WS_PART + (size_t)blk * PART_STRIDE;
    part[t] = cc;
    if (t == 0) {
        float bbv = pbv[0]; int bbi = pbi[0];
        #pragma unroll
        for (int i = 1; i < 4; ++i)
            if (pbv[i] > bbv || (pbv[i] == bbv && pbi[i] < bbi)) { bbv = pbv[i]; bbi = pbi[i]; }
        part[256] = M4; part[257] = Lc; part[258] = bbv; part[259] = (float)bbi;
    }
}

// ---------------- Kernel C: combine partials + projections + scatter ----------------
__global__ __launch_bounds__(256) void finalize(
    const float* __restrict__ W2, const float* __restrict__ b2,
    const float* __restrict__ W3, const float* __restrict__ b3,
    float* __restrict__ ws, float* __restrict__ out)
{
    const int b = blockIdx.x, t = threadIdx.x;
    const int w = t >> 6, lane = t & 63;
    __shared__ float marr[256], mred[256], lred[256], e_sh[256], bvred[256];
    __shared__ int bired[256];
    __shared__ __align__(16) float cat[2 * HH];   // [ctx_raw | hn]
    __shared__ __align__(16) float cat2[2 * HH];  // [context | hn]

    const float* parts = ws + WS_PART + (size_t)b * CHUNKS_PER_B * PART_STRIDE;
    {
        const float* p = parts + (size_t)t * PART_STRIDE + 256;
        float mv = p[0];
        marr[t] = mv; mred[t] = mv;
        lred[t] = p[1];
        bvred[t] = p[2]; bired[t] = (int)p[3];
    }
    __syncthreads();
    for (int s = 128; s > 0; s >>= 1) {
        if (t < s) {
            mred[t] = fmaxf(mred[t], mred[t + s]);
            if (bvred[t + s] > bvred[t] ||
                (bvred[t + s] == bvred[t] && bired[t + s] < bired[t])) {
                bvred[t] = bvred[t + s]; bired[t] = bired[t + s];
            }
        }
        __syncthreads();
    }
    const float M = mred[0];
    float lraw = lred[t];
    __syncthreads();
    {
        float e = __expf(marr[t] - M);
        e_sh[t] = e;
        lred[t] = lraw * e;
    }
    __syncthreads();
    for (int s = 128; s > 0; s >>= 1) {
        if (t < s) lred[t] += lred[t + s];
        __syncthreads();
    }
    const float L = lred[0];
    const int best = bired[0];

    // ctx_raw[t] = (sum_c part_c[t] * e_c) / L
    float acc = 0.0f;
    #pragma unroll 16
    for (int c = 0; c < CHUNKS_PER_B; ++c)
        acc += parts[(size_t)c * PART_STRIDE + t] * e_sh[c];
    const float hnv = ws[WS_HNEW + b * HH + t];
    cat[t] = acc / L;
    cat[HH + t] = hnv;
    cat2[HH + t] = hnv;
    __syncthreads();

    // context = W2 . ctx_raw + b2 : wave-per-4-rows, coalesced row loads
    {
        const float4* v4 = (const float4*)cat;   // 64 float4 of ctx_raw
        const float4 vv = v4[lane];
        #pragma unroll 4
        for (int grp = 0; grp < 16; ++grp) {
            const int rbase = w * 64 + grp * 4;
            float4 w0 = ((const float4*)(W2 + (size_t)(rbase + 0) * HH))[lane];
            float4 w1 = ((const float4*)(W2 + (size_t)(rbase + 1) * HH))[lane];
            float4 w2v = ((const float4*)(W2 + (size_t)(rbase + 2) * HH))[lane];
            float4 w3v = ((const float4*)(W2 + (size_t)(rbase + 3) * HH))[lane];
            float r = merge4(dot4(w0, vv), dot4(w1, vv), dot4(w2v, vv), dot4(w3v, vv), lane);
            if (lane < 4)
                cat2[rbase + lane] = r + b2[rbase + lane];
        }
    }
    __syncthreads();

    // result = W3 . [context, hn] + b3 : rows are 512 wide
    {
        const float4* c4 = (const float4*)cat2;  // 128 float4
        const float4 clo = c4[lane], chi = c4[lane + 64];
        #pragma unroll 4
        for (int grp = 0; grp < 16; ++grp) {
            const int rbase = w * 64 + grp * 4;
            float p[4];
            #pragma unroll
            for (int i = 0; i < 4; ++i) {
                const float4* row = (const float4*)(W3 + (size_t)(rbase + i) * 2 * HH);
                p[i] = dot4(row[lane], clo) + dot4(row[lane + 64], chi);
            }
            float r = merge4(p[0], p[1], p[2], p[3], lane);
            if (lane < 4)
                out[OUT_RESULT + b * HH + rbase + lane] = r + b3[rbase + lane];
        }
    }

    if (t == 0) {
        out[OUT_EV + b] = (float)best;
        out[OUT_MASK + (size_t)b * SS + best] = NEGV;
    }
}

extern "C" void kernel_launch(void* const* d_in, const int* in_sizes, int n_in,
                              void* d_out, int out_size, void* d_ws, size_t ws_size,
                              hipStream_t stream) {
    const float* last_hidden = (const float*)d_in[0];
    const float* dec         = (const float*)d_in[1];
    const float* eo          = (const float*)d_in[2];
    const float* mask        = (const float*)d_in[3];
    const float* gum         = (const float*)d_in[4];
    const float* W1          = (const float*)d_in[5];
    const float* b1          = (const float*)d_in[6];
    const float* W2          = (const float*)d_in[7];
    const float* b2          = (const float*)d_in[8];
    const float* W3          = (const float*)d_in[9];
    const float* b3          = (const float*)d_in[10];
    const float* W_ih        = (const float*)d_in[11];
    const float* W_hh        = (const float*)d_in[12];
    const float* b_ih        = (const float*)d_in[13];
    const float* b_hh        = (const float*)d_in[14];
    float* out = (float*)d_out;
    float* ws  = (float*)d_ws;

    hipLaunchKernelGGL(gates_gemv, dim3(192), dim3(256), 0, stream,
                       dec, last_hidden, W_ih, W_hh, ws);
    hipLaunchKernelGGL(gru_q1, dim3(64), dim3(256), 0, stream,
                       last_hidden, W1, b1, b_ih, b_hh, ws, out);
    hipLaunchKernelGGL(attn_main, dim3(BB * CHUNKS_PER_B), dim3(256), 0, stream,
                       eo, mask, gum, ws, out);
    hipLaunchKernelGGL(finalize, dim3(BB), dim3(256), 0, stream,
                       W2, b2, W3, b3, ws, out);
}

// Round 8
// 87.894 us; speedup vs baseline: 1.5473x; 1.3295x over previous
//
#include <hip/hip_runtime.h>
#include <math.h>

// Problem constants
#define HH 256
#define SS 32768
#define BB 8
#define NEGV (-10000000000.0f)

// Output layout (floats): result(2048) | h_new(2048) | evidence(8) | attn(262144) | new_mask(262144)
#define OUT_RESULT 0
#define OUT_HNEW   2048
#define OUT_EV     4096
#define OUT_ATT    4104
#define OUT_MASK   266248

// Workspace layout (floats)
#define WS_HNEW  0
#define WS_Q1    2048
#define WS_C1    4096              // 8 floats
#define WS_GATES 4112              // 1536 rows x 8 batches (transposed gates)
#define WS_PART  (4112 + 12288)    // 16400
#define PART_STRIDE 264            // ctx[256] + m,l,bestv,bestidx (+pad)
#define CHUNKS_PER_B 128           // 128 chunks * 256 s = 32768
#define S_PER_BLOCK 256
#define S_PER_WAVE 64

__device__ __forceinline__ float rl(float x, int srclane) {
    return __int_as_float(__builtin_amdgcn_readlane(__float_as_int(x), srclane));
}
__device__ __forceinline__ float dot4(float4 a, float4 b) {
    return a.x * b.x + a.y * b.y + a.z * b.z + a.w * b.w;
}
// merged 4-way wave reduction: 7 shuffles; lanes with lane%4==i hold full sum of p_i
__device__ __forceinline__ float merge4(float p0, float p1, float p2, float p3, int lane) {
    const bool lb0 = lane & 1;
    float r01 = (lb0 ? p1 : p0) + __shfl_xor(lb0 ? p0 : p1, 1);
    float r23 = (lb0 ? p3 : p2) + __shfl_xor(lb0 ? p2 : p3, 1);
    const bool lb1 = lane & 2;
    float r = (lb1 ? r23 : r01) + __shfl_xor(lb1 ? r01 : r23, 2);
    r += __shfl_xor(r, 4);
    r += __shfl_xor(r, 8);
    r += __shfl_xor(r, 16);
    r += __shfl_xor(r, 32);
    return r;
}

// ---------------- Kernel A1: row-parallel gates GEMV (192 blocks x 8 rows) ----------------
__global__ __launch_bounds__(256) void gates_gemv(
    const float* __restrict__ dec_in, const float* __restrict__ last_hidden,
    const float* __restrict__ W_ih, const float* __restrict__ W_hh,
    float* __restrict__ ws)
{
    const int t = threadIdx.x;
    const int w = t >> 6, lane = t & 63;
    const bool ih = (blockIdx.x < 96);

    __shared__ __align__(16) float4 s4[BB][HH / 4];
    {
        const float* src = ih ? dec_in : last_hidden;
        float* sf = (float*)s4;
        #pragma unroll
        for (int i = 0; i < 8; ++i)
            sf[i * 256 + t] = src[i * 256 + t];
    }
    __syncthreads();

    const int local = ih ? blockIdx.x : (blockIdx.x - 96);
    const int rbase = local * 8 + w * 2;
    const float* W = ih ? W_ih : W_hh;

    #pragma unroll
    for (int rr = 0; rr < 2; ++rr) {
        const int r = rbase + rr;
        const float4 rv = ((const float4*)(W + (size_t)r * HH))[lane];

        float p[8];
        #pragma unroll
        for (int b = 0; b < 8; ++b)
            p[b] = dot4(rv, s4[b][lane]);

        // merged 8-way butterfly: 10 shuffles; lane&7==b holds full dot for batch b
        const bool l1 = lane & 1;
        float q01 = (l1 ? p[1] : p[0]) + __shfl_xor(l1 ? p[0] : p[1], 1);
        float q23 = (l1 ? p[3] : p[2]) + __shfl_xor(l1 ? p[2] : p[3], 1);
        float q45 = (l1 ? p[5] : p[4]) + __shfl_xor(l1 ? p[4] : p[5], 1);
        float q67 = (l1 ? p[7] : p[6]) + __shfl_xor(l1 ? p[6] : p[7], 1);
        const bool l2 = lane & 2;
        float r03 = (l2 ? q23 : q01) + __shfl_xor(l2 ? q01 : q23, 2);
        float r47 = (l2 ? q67 : q45) + __shfl_xor(l2 ? q45 : q67, 2);
        const bool l4 = lane & 4;
        float s = (l4 ? r47 : r03) + __shfl_xor(l4 ? r03 : r47, 4);
        s += __shfl_xor(s, 8);
        s += __shfl_xor(s, 16);
        s += __shfl_xor(s, 32);

        if (lane < 8)
            ws[WS_GATES + (size_t)(ih ? r : 768 + r) * 8 + lane] = s;
    }
}

// ---------------- Kernel A2: GRU combine + q1/c1 (64 blocks = 8 batch x 8 colgroups) ----
__global__ __launch_bounds__(256) void gru_q1(
    const float* __restrict__ last_hidden,
    const float* __restrict__ W1, const float* __restrict__ b1,
    const float* __restrict__ b_ih, const float* __restrict__ b_hh,
    float* __restrict__ ws, float* __restrict__ out)
{
    const int blk = blockIdx.x;
    const int b = blk >> 3;        // batch
    const int cg = blk & 7;        // k-column group [cg*32, cg*32+32)
    const int t = threadIdx.x;
    __shared__ float hn[HH];
    __shared__ float qpart[8][32];
    __shared__ float red[256];

    const float* gT = ws + WS_GATES;
    float gi0 = gT[(size_t)(t)         * 8 + b] + b_ih[t];
    float gi1 = gT[(size_t)(t + HH)    * 8 + b] + b_ih[t + HH];
    float gi2 = gT[(size_t)(t + 2*HH)  * 8 + b] + b_ih[t + 2*HH];
    float gh0 = gT[(size_t)(768 + t)        * 8 + b] + b_hh[t];
    float gh1 = gT[(size_t)(768 + t + HH)   * 8 + b] + b_hh[t + HH];
    float gh2 = gT[(size_t)(768 + t + 2*HH) * 8 + b] + b_hh[t + 2*HH];

    const float hprev = last_hidden[b * HH + t];
    float r = 1.0f / (1.0f + expf(-(gi0 + gh0)));
    float z = 1.0f / (1.0f + expf(-(gi1 + gh1)));
    float n = tanhf(gi2 + r * gh2);
    float hnew = (1.0f - z) * n + z * hprev;

    hn[t] = hnew;
    red[t] = hnew * b1[t];
    if (cg == 0) {
        ws[WS_HNEW + b * HH + t] = hnew;
        out[OUT_HNEW + b * HH + t] = hnew;
    }
    __syncthreads();

    // q1 partial: thread (kl, hg) sums 32 h values for column k
    const int kl = t & 31, hg = t >> 5;
    const int k = cg * 32 + kl;
    float acc = 0.0f;
    #pragma unroll 8
    for (int j = 0; j < 32; ++j) {
        int h = hg * 32 + j;
        acc += hn[h] * W1[(size_t)h * HH + k];
    }
    qpart[hg][kl] = acc;
    __syncthreads();
    if (t < 32) {
        float s = 0.0f;
        #pragma unroll
        for (int j = 0; j < 8; ++j) s += qpart[j][t];
        ws[WS_Q1 + b * HH + cg * 32 + t] = s;
    }

    if (cg == 0) {   // block-uniform branch: barriers legal
        for (int s = 128; s > 0; s >>= 1) {
            if (t < s) red[t] += red[t + s];
            __syncthreads();
        }
        if (t == 0) ws[WS_C1 + b] = red[0];
    }
}

// ---------------- Kernel B: streaming scores + online softmax context ----------------
// R5 inner loop, XCD-chunked block mapping: XCD x owns batch x (contiguous 32MB).
__global__ __launch_bounds__(256, 4) void attn_main(
    const float* __restrict__ eo, const float* __restrict__ mask,
    const float* __restrict__ gum, float* __restrict__ ws,
    float* __restrict__ out)
{
    const int bid = blockIdx.x;
    const int lin = (bid & 7) * 128 + (bid >> 3);   // bijective: 1024 blocks, 8 XCDs
    const int b = lin >> 7;            // CHUNKS_PER_B = 128
    const int chunk = lin & 127;
    const int blk = lin;               // for part indexing
    const int t = threadIdx.x;
    const int w = t >> 6, lane = t & 63;
    const int sbase = chunk * S_PER_BLOCK;
    const int swave = sbase + w * S_PER_WAVE;

    // mask pass-through copy (evidence slot overwritten by finalize)
    out[OUT_MASK + (size_t)b * SS + sbase + t] = mask[(size_t)b * SS + sbase + t];

    const float4 q = ((const float4*)(ws + WS_Q1 + b * HH))[lane];
    const float c1 = ws[WS_C1 + b];

    const float mk = mask[(size_t)b * SS + swave + lane];
    const float uu = gum[(size_t)b * SS + swave + lane];
    const float gl = -logf(-logf(uu));

    const float4* base = (const float4*)(eo + ((size_t)b * SS + swave) * HH);

    float m = -INFINITY, l = 0.0f;
    float bv = -INFINITY; int bi = 0;
    float4 ctx = {0.f, 0.f, 0.f, 0.f};
    float my_t = 0.0f;

    auto body = [&](float4 a0, float4 a1, float4 a2, float4 a3, int g) {
        float p0 = dot4(a0, q), p1 = dot4(a1, q);
        float p2 = dot4(a2, q), p3 = dot4(a3, q);
        float r = merge4(p0, p1, p2, p3, lane);

        float tg0, tg1, tg2, tg3;
        #pragma unroll
        for (int i = 0; i < 4; ++i) {
            float d  = rl(r, i);
            float tt = d + c1 + rl(mk, 4 * g + i);
            if (lane == 4 * g + i) my_t = tt;
            float tgi = tt + rl(gl, 4 * g + i);
            if (tgi > bv) { bv = tgi; bi = swave + 4 * g + i; }  // first-max tie-break
            if (i == 0) tg0 = tgi; else if (i == 1) tg1 = tgi;
            else if (i == 2) tg2 = tgi; else tg3 = tgi;
        }

        float gmax = fmaxf(fmaxf(tg0, tg1), fmaxf(tg2, tg3));
        if (gmax > m) {                           // wave-uniform
            float sc = __expf(m - gmax);
            l *= sc; ctx.x *= sc; ctx.y *= sc; ctx.z *= sc; ctx.w *= sc;
            m = gmax;
        }
        float w0 = __expf(tg0 - m), w1 = __expf(tg1 - m);
        float w2 = __expf(tg2 - m), w3 = __expf(tg3 - m);
        l += (w0 + w1) + (w2 + w3);
        ctx.x += w0*a0.x + w1*a1.x + w2*a2.x + w3*a3.x;
        ctx.y += w0*a0.y + w1*a1.y + w2*a2.y + w3*a3.y;
        ctx.z += w0*a0.z + w1*a1.z + w2*a2.z + w3*a3.z;
        ctx.w += w0*a0.w + w1*a1.w + w2*a2.w + w3*a3.w;
    };

    // prefetch group 0 (4 rows = 4KB/wave), 16 groups total
    float4 a0 = base[0 * 64 + lane];
    float4 a1 = base[1 * 64 + lane];
    float4 a2 = base[2 * 64 + lane];
    float4 a3 = base[3 * 64 + lane];

    #pragma unroll 3
    for (int g = 0; g < 15; ++g) {
        const float4* nb = base + (size_t)(g + 1) * 4 * 64;
        float4 n0 = nb[0 * 64 + lane];
        float4 n1 = nb[1 * 64 + lane];
        float4 n2 = nb[2 * 64 + lane];
        float4 n3 = nb[3 * 64 + lane];
        body(a0, a1, a2, a3, g);
        a0 = n0; a1 = n1; a2 = n2; a3 = n3;
    }
    body(a0, a1, a2, a3, 15);

    out[OUT_ATT + (size_t)b * SS + swave + lane] = my_t;

    // combine 4 waves -> 1 block partial
    __shared__ float pm[4], pl[4], pbv[4];
    __shared__ int pbi[4];
    __shared__ __align__(16) float pctx[4][HH];
    ((float4*)pctx[w])[lane] = ctx;
    if (lane == 0) { pm[w] = m; pl[w] = l; pbv[w] = bv; pbi[w] = bi; }
    __syncthreads();

    float M4 = fmaxf(fmaxf(pm[0], pm[1]), fmaxf(pm[2], pm[3]));
    float e0 = __expf(pm[0] - M4), e1 = __expf(pm[1] - M4);
    float e2 = __expf(pm[2] - M4), e3 = __expf(pm[3] - M4);
    float Lc = pl[0]*e0 + pl[1]*e1 + pl[2]*e2 + pl[3]*e3;
    float cc = pctx[0][t]*e0 + pctx[1][t]*e1 + pctx[2][t]*e2 + pctx[3][t]*e3;

    float* part = ws + WS_PART + (size_t)blk * PART_STRIDE;
    part[t] = cc;
    if (t == 0) {
        float bbv = pbv[0]; int bbi = pbi[0];
        #pragma unroll
        for (int i = 1; i < 4; ++i)
            if (pbv[i] > bbv || (pbv[i] == bbv && pbi[i] < bbi)) { bbv = pbv[i]; bbi = pbi[i]; }
        part[256] = M4; part[257] = Lc; part[258] = bbv; part[259] = (float)bbi;
    }
}

// ---------------- Kernel C: combine partials + projections + scatter ----------------
__global__ __launch_bounds__(256) void finalize(
    const float* __restrict__ W2, const float* __restrict__ b2,
    const float* __restrict__ W3, const float* __restrict__ b3,
    float* __restrict__ ws, float* __restrict__ out)
{
    const int b = blockIdx.x, t = threadIdx.x;
    const int w = t >> 6, lane = t & 63;
    __shared__ float marr[128], mred[128], lred[128], e_sh[128], bvred[128];
    __shared__ int bired[128];
    __shared__ __align__(16) float cat[2 * HH];   // [ctx_raw | hn]
    __shared__ __align__(16) float cat2[2 * HH];  // [context | hn]

    const float* parts = ws + WS_PART + (size_t)b * CHUNKS_PER_B * PART_STRIDE;
    float lraw = 0.0f;
    if (t < 128) {
        const float* p = parts + (size_t)t * PART_STRIDE + 256;
        float mv = p[0]; lraw = p[1];
        marr[t] = mv; mred[t] = mv;
        bvred[t] = p[2]; bired[t] = (int)p[3];
    }
    __syncthreads();
    for (int s = 64; s > 0; s >>= 1) {
        if (t < s) {
            mred[t] = fmaxf(mred[t], mred[t + s]);
            if (bvred[t + s] > bvred[t] ||
                (bvred[t + s] == bvred[t] && bired[t + s] < bired[t])) {
                bvred[t] = bvred[t + s]; bired[t] = bired[t + s];
            }
        }
        __syncthreads();
    }
    const float M = mred[0];
    if (t < 128) {
        float e = __expf(marr[t] - M);
        e_sh[t] = e;
        lred[t] = lraw * e;
    }
    __syncthreads();
    for (int s = 64; s > 0; s >>= 1) {
        if (t < s) lred[t] += lred[t + s];
        __syncthreads();
    }
    const float L = lred[0];
    const int best = bired[0];

    // ctx_raw[t] = (sum_c part_c[t] * e_c) / L
    float acc = 0.0f;
    #pragma unroll 16
    for (int c = 0; c < CHUNKS_PER_B; ++c)
        acc += parts[(size_t)c * PART_STRIDE + t] * e_sh[c];
    const float hnv = ws[WS_HNEW + b * HH + t];
    cat[t] = acc / L;
    cat[HH + t] = hnv;
    cat2[HH + t] = hnv;
    __syncthreads();

    // context = W2 . ctx_raw + b2 : wave-per-4-rows, coalesced row loads
    {
        const float4* v4 = (const float4*)cat;   // 64 float4 of ctx_raw
        const float4 vv = v4[lane];
        #pragma unroll 4
        for (int grp = 0; grp < 16; ++grp) {
            const int rbase = w * 64 + grp * 4;
            float4 w0 = ((const float4*)(W2 + (size_t)(rbase + 0) * HH))[lane];
            float4 w1 = ((const float4*)(W2 + (size_t)(rbase + 1) * HH))[lane];
            float4 w2v = ((const float4*)(W2 + (size_t)(rbase + 2) * HH))[lane];
            float4 w3v = ((const float4*)(W2 + (size_t)(rbase + 3) * HH))[lane];
            float r = merge4(dot4(w0, vv), dot4(w1, vv), dot4(w2v, vv), dot4(w3v, vv), lane);
            if (lane < 4)
                cat2[rbase + lane] = r + b2[rbase + lane];
        }
    }
    __syncthreads();

    // result = W3 . [context, hn] + b3 : rows are 512 wide
    {
        const float4* c4 = (const float4*)cat2;  // 128 float4
        const float4 clo = c4[lane], chi = c4[lane + 64];
        #pragma unroll 4
        for (int grp = 0; grp < 16; ++grp) {
            const int rbase = w * 64 + grp * 4;
            float p[4];
            #pragma unroll
            for (int i = 0; i < 4; ++i) {
                const float4* row = (const float4*)(W3 + (size_t)(rbase + i) * 2 * HH);
                p[i] = dot4(row[lane], clo) + dot4(row[lane + 64], chi);
            }
            float r = merge4(p[0], p[1], p[2], p[3], lane);
            if (lane < 4)
                out[OUT_RESULT + b * HH + rbase + lane] = r + b3[rbase + lane];
        }
    }

    if (t == 0) {
        out[OUT_EV + b] = (float)best;
        out[OUT_MASK + (size_t)b * SS + best] = NEGV;
    }
}

extern "C" void kernel_launch(void* const* d_in, const int* in_sizes, int n_in,
                              void* d_out, int out_size, void* d_ws, size_t ws_size,
                              hipStream_t stream) {
    const float* last_hidden = (const float*)d_in[0];
    const float* dec         = (const float*)d_in[1];
    const float* eo          = (const float*)d_in[2];
    const float* mask        = (const float*)d_in[3];
    const float* gum         = (const float*)d_in[4];
    const float* W1          = (const float*)d_in[5];
    const float* b1          = (const float*)d_in[6];
    const float* W2          = (const float*)d_in[7];
    const float* b2          = (const float*)d_in[8];
    const float* W3          = (const float*)d_in[9];
    const float* b3          = (const float*)d_in[10];
    const float* W_ih        = (const float*)d_in[11];
    const float* W_hh        = (const float*)d_in[12];
    const float* b_ih        = (const float*)d_in[13];
    const float* b_hh        = (const float*)d_in[14];
    float* out = (float*)d_out;
    float* ws  = (float*)d_ws;

    hipLaunchKernelGGL(gates_gemv, dim3(192), dim3(256), 0, stream,
                       dec, last_hidden, W_ih, W_hh, ws);
    hipLaunchKernelGGL(gru_q1, dim3(64), dim3(256), 0, stream,
                       last_hidden, W1, b1, b_ih, b_hh, ws, out);
    hipLaunchKernelGGL(attn_main, dim3(BB * CHUNKS_PER_B), dim3(256), 0, stream,
                       eo, mask, gum, ws, out);
    hipLaunchKernelGGL(finalize, dim3(BB), dim3(256), 0, stream,
                       W2, b2, W3, b3, ws, out);
}

// Round 9
// 78.675 us; speedup vs baseline: 1.7286x; 1.1172x over previous
//
#include <hip/hip_runtime.h>
#include <math.h>

// Problem constants
#define HH 256
#define SS 32768
#define BB 8
#define NEGV (-10000000000.0f)

// Output layout (floats): result(2048) | h_new(2048) | evidence(8) | attn(262144) | new_mask(262144)
#define OUT_RESULT 0
#define OUT_HNEW   2048
#define OUT_EV     4096
#define OUT_ATT    4104
#define OUT_MASK   266248

// Workspace layout (floats)
#define WS_HNEW  0
#define WS_Q1    2048
#define WS_C1    4096              // 8 floats
#define WS_GATES 4112              // 1536 rows x 8 batches (transposed gates)
#define WS_PART  (4112 + 12288)    // 16400
#define PART_STRIDE 264            // ctx[256] + m,l,bestv,bestidx (+pad)
#define CHUNKS_PER_B 128           // 128 chunks * 256 s = 32768
#define S_PER_BLOCK 256
#define S_PER_WAVE 64

typedef float vf4 __attribute__((ext_vector_type(4)));

__device__ __forceinline__ float rl(float x, int srclane) {
    return __int_as_float(__builtin_amdgcn_readlane(__float_as_int(x), srclane));
}
__device__ __forceinline__ float dot4(float4 a, float4 b) {
    return a.x * b.x + a.y * b.y + a.z * b.z + a.w * b.w;
}
__device__ __forceinline__ float dot4v(vf4 a, vf4 b) {
    return a[0] * b[0] + a[1] * b[1] + a[2] * b[2] + a[3] * b[3];
}
__device__ __forceinline__ vf4 ntload(const vf4* p) {
    return __builtin_nontemporal_load(p);
}
// merged 4-way wave reduction: 7 shuffles; lanes with lane%4==i hold full sum of p_i
__device__ __forceinline__ float merge4(float p0, float p1, float p2, float p3, int lane) {
    const bool lb0 = lane & 1;
    float r01 = (lb0 ? p1 : p0) + __shfl_xor(lb0 ? p0 : p1, 1);
    float r23 = (lb0 ? p3 : p2) + __shfl_xor(lb0 ? p2 : p3, 1);
    const bool lb1 = lane & 2;
    float r = (lb1 ? r23 : r01) + __shfl_xor(lb1 ? r01 : r23, 2);
    r += __shfl_xor(r, 4);
    r += __shfl_xor(r, 8);
    r += __shfl_xor(r, 16);
    r += __shfl_xor(r, 32);
    return r;
}

// ---------------- Kernel A1: row-parallel gates GEMV (192 blocks x 8 rows) ----------------
__global__ __launch_bounds__(256) void gates_gemv(
    const float* __restrict__ dec_in, const float* __restrict__ last_hidden,
    const float* __restrict__ W_ih, const float* __restrict__ W_hh,
    float* __restrict__ ws)
{
    const int t = threadIdx.x;
    const int w = t >> 6, lane = t & 63;
    const bool ih = (blockIdx.x < 96);

    __shared__ __align__(16) float4 s4[BB][HH / 4];
    {
        const float* src = ih ? dec_in : last_hidden;
        float* sf = (float*)s4;
        #pragma unroll
        for (int i = 0; i < 8; ++i)
            sf[i * 256 + t] = src[i * 256 + t];
    }
    __syncthreads();

    const int local = ih ? blockIdx.x : (blockIdx.x - 96);
    const int rbase = local * 8 + w * 2;
    const float* W = ih ? W_ih : W_hh;

    #pragma unroll
    for (int rr = 0; rr < 2; ++rr) {
        const int r = rbase + rr;
        const float4 rv = ((const float4*)(W + (size_t)r * HH))[lane];

        float p[8];
        #pragma unroll
        for (int b = 0; b < 8; ++b)
            p[b] = dot4(rv, s4[b][lane]);

        // merged 8-way butterfly: 10 shuffles; lane&7==b holds full dot for batch b
        const bool l1 = lane & 1;
        float q01 = (l1 ? p[1] : p[0]) + __shfl_xor(l1 ? p[0] : p[1], 1);
        float q23 = (l1 ? p[3] : p[2]) + __shfl_xor(l1 ? p[2] : p[3], 1);
        float q45 = (l1 ? p[5] : p[4]) + __shfl_xor(l1 ? p[4] : p[5], 1);
        float q67 = (l1 ? p[7] : p[6]) + __shfl_xor(l1 ? p[6] : p[7], 1);
        const bool l2 = lane & 2;
        float r03 = (l2 ? q23 : q01) + __shfl_xor(l2 ? q01 : q23, 2);
        float r47 = (l2 ? q67 : q45) + __shfl_xor(l2 ? q45 : q67, 2);
        const bool l4 = lane & 4;
        float s = (l4 ? r47 : r03) + __shfl_xor(l4 ? r03 : r47, 4);
        s += __shfl_xor(s, 8);
        s += __shfl_xor(s, 16);
        s += __shfl_xor(s, 32);

        if (lane < 8)
            ws[WS_GATES + (size_t)(ih ? r : 768 + r) * 8 + lane] = s;
    }
}

// ---------------- Kernel A2: GRU combine + q1/c1 (64 blocks = 8 batch x 8 colgroups) ----
__global__ __launch_bounds__(256) void gru_q1(
    const float* __restrict__ last_hidden,
    const float* __restrict__ W1, const float* __restrict__ b1,
    const float* __restrict__ b_ih, const float* __restrict__ b_hh,
    float* __restrict__ ws, float* __restrict__ out)
{
    const int blk = blockIdx.x;
    const int b = blk >> 3;        // batch
    const int cg = blk & 7;        // k-column group [cg*32, cg*32+32)
    const int t = threadIdx.x;
    __shared__ float hn[HH];
    __shared__ float qpart[8][32];
    __shared__ float red[256];

    const float* gT = ws + WS_GATES;
    float gi0 = gT[(size_t)(t)         * 8 + b] + b_ih[t];
    float gi1 = gT[(size_t)(t + HH)    * 8 + b] + b_ih[t + HH];
    float gi2 = gT[(size_t)(t + 2*HH)  * 8 + b] + b_ih[t + 2*HH];
    float gh0 = gT[(size_t)(768 + t)        * 8 + b] + b_hh[t];
    float gh1 = gT[(size_t)(768 + t + HH)   * 8 + b] + b_hh[t + HH];
    float gh2 = gT[(size_t)(768 + t + 2*HH) * 8 + b] + b_hh[t + 2*HH];

    const float hprev = last_hidden[b * HH + t];
    float r = 1.0f / (1.0f + expf(-(gi0 + gh0)));
    float z = 1.0f / (1.0f + expf(-(gi1 + gh1)));
    float n = tanhf(gi2 + r * gh2);
    float hnew = (1.0f - z) * n + z * hprev;

    hn[t] = hnew;
    red[t] = hnew * b1[t];
    if (cg == 0) {
        ws[WS_HNEW + b * HH + t] = hnew;
        out[OUT_HNEW + b * HH + t] = hnew;
    }
    __syncthreads();

    // q1 partial: thread (kl, hg) sums 32 h values for column k
    const int kl = t & 31, hg = t >> 5;
    const int k = cg * 32 + kl;
    float acc = 0.0f;
    #pragma unroll 8
    for (int j = 0; j < 32; ++j) {
        int h = hg * 32 + j;
        acc += hn[h] * W1[(size_t)h * HH + k];
    }
    qpart[hg][kl] = acc;
    __syncthreads();
    if (t < 32) {
        float s = 0.0f;
        #pragma unroll
        for (int j = 0; j < 8; ++j) s += qpart[j][t];
        ws[WS_Q1 + b * HH + cg * 32 + t] = s;
    }

    if (cg == 0) {   // block-uniform branch: barriers legal
        for (int s = 128; s > 0; s >>= 1) {
            if (t < s) red[t] += red[t + s];
            __syncthreads();
        }
        if (t == 0) ws[WS_C1 + b] = red[0];
    }
}

// ---------------- Kernel B: streaming scores + online softmax context ----------------
// R5 inner loop + XCD-chunked mapping + NONTEMPORAL eo loads (read-once stream).
__global__ __launch_bounds__(256, 4) void attn_main(
    const float* __restrict__ eo, const float* __restrict__ mask,
    const float* __restrict__ gum, float* __restrict__ ws,
    float* __restrict__ out)
{
    const int bid = blockIdx.x;
    const int lin = (bid & 7) * 128 + (bid >> 3);   // bijective: 1024 blocks, 8 XCDs
    const int b = lin >> 7;            // CHUNKS_PER_B = 128
    const int chunk = lin & 127;
    const int blk = lin;               // for part indexing
    const int t = threadIdx.x;
    const int w = t >> 6, lane = t & 63;
    const int sbase = chunk * S_PER_BLOCK;
    const int swave = sbase + w * S_PER_WAVE;

    // mask pass-through copy (evidence slot overwritten by finalize)
    out[OUT_MASK + (size_t)b * SS + sbase + t] = mask[(size_t)b * SS + sbase + t];

    const vf4 q = ((const vf4*)(ws + WS_Q1 + b * HH))[lane];
    const float c1 = ws[WS_C1 + b];

    const float mk = mask[(size_t)b * SS + swave + lane];
    const float uu = gum[(size_t)b * SS + swave + lane];
    const float gl = -logf(-logf(uu));

    const vf4* base = (const vf4*)(eo + ((size_t)b * SS + swave) * HH);

    float m = -INFINITY, l = 0.0f;
    float bv = -INFINITY; int bi = 0;
    vf4 ctx = {0.f, 0.f, 0.f, 0.f};
    float my_t = 0.0f;

    auto body = [&](vf4 a0, vf4 a1, vf4 a2, vf4 a3, int g) {
        float p0 = dot4v(a0, q), p1 = dot4v(a1, q);
        float p2 = dot4v(a2, q), p3 = dot4v(a3, q);
        float r = merge4(p0, p1, p2, p3, lane);

        float tg0, tg1, tg2, tg3;
        #pragma unroll
        for (int i = 0; i < 4; ++i) {
            float d  = rl(r, i);
            float tt = d + c1 + rl(mk, 4 * g + i);
            if (lane == 4 * g + i) my_t = tt;
            float tgi = tt + rl(gl, 4 * g + i);
            if (tgi > bv) { bv = tgi; bi = swave + 4 * g + i; }  // first-max tie-break
            if (i == 0) tg0 = tgi; else if (i == 1) tg1 = tgi;
            else if (i == 2) tg2 = tgi; else tg3 = tgi;
        }

        float gmax = fmaxf(fmaxf(tg0, tg1), fmaxf(tg2, tg3));
        if (gmax > m) {                           // wave-uniform
            float sc = __expf(m - gmax);
            l *= sc; ctx *= sc;
            m = gmax;
        }
        float w0 = __expf(tg0 - m), w1 = __expf(tg1 - m);
        float w2 = __expf(tg2 - m), w3 = __expf(tg3 - m);
        l += (w0 + w1) + (w2 + w3);
        ctx += w0 * a0 + w1 * a1 + w2 * a2 + w3 * a3;
    };

    // prefetch group 0 (4 rows = 4KB/wave), 16 groups total; nontemporal reads
    vf4 a0 = ntload(base + 0 * 64 + lane);
    vf4 a1 = ntload(base + 1 * 64 + lane);
    vf4 a2 = ntload(base + 2 * 64 + lane);
    vf4 a3 = ntload(base + 3 * 64 + lane);

    #pragma unroll 3
    for (int g = 0; g < 15; ++g) {
        const vf4* nb = base + (size_t)(g + 1) * 4 * 64;
        vf4 n0 = ntload(nb + 0 * 64 + lane);
        vf4 n1 = ntload(nb + 1 * 64 + lane);
        vf4 n2 = ntload(nb + 2 * 64 + lane);
        vf4 n3 = ntload(nb + 3 * 64 + lane);
        body(a0, a1, a2, a3, g);
        a0 = n0; a1 = n1; a2 = n2; a3 = n3;
    }
    body(a0, a1, a2, a3, 15);

    out[OUT_ATT + (size_t)b * SS + swave + lane] = my_t;

    // combine 4 waves -> 1 block partial
    __shared__ float pm[4], pl[4], pbv[4];
    __shared__ int pbi[4];
    __shared__ __align__(16) float pctx[4][HH];
    ((vf4*)pctx[w])[lane] = ctx;
    if (lane == 0) { pm[w] = m; pl[w] = l; pbv[w] = bv; pbi[w] = bi; }
    __syncthreads();

    float M4 = fmaxf(fmaxf(pm[0], pm[1]), fmaxf(pm[2], pm[3]));
    float e0 = __expf(pm[0] - M4), e1 = __expf(pm[1] - M4);
    float e2 = __expf(pm[2] - M4), e3 = __expf(pm[3] - M4);
    float Lc = pl[0]*e0 + pl[1]*e1 + pl[2]*e2 + pl[3]*e3;
    float cc = pctx[0][t]*e0 + pctx[1][t]*e1 + pctx[2][t]*e2 + pctx[3][t]*e3;

    float* part = ws + WS_PART + (size_t)blk * PART_STRIDE;
    part[t] = cc;
    if (t == 0) {
        float bbv = pbv[0]; int bbi = pbi[0];
        #pragma unroll
        for (int i = 1; i < 4; ++i)
            if (pbv[i] > bbv || (pbv[i] == bbv && pbi[i] < bbi)) { bbv = pbv[i]; bbi = pbi[i]; }
        part[256] = M4; part[257] = Lc; part[258] = bbv; part[259] = (float)bbi;
    }
}

// ---------------- Kernel C: combine partials + projections + scatter ----------------
__global__ __launch_bounds__(256) void finalize(
    const float* __restrict__ W2, const float* __restrict__ b2,
    const float* __restrict__ W3, const float* __restrict__ b3,
    float* __restrict__ ws, float* __restrict__ out)
{
    const int b = blockIdx.x, t = threadIdx.x;
    const int w = t >> 6, lane = t & 63;
    __shared__ float marr[128], mred[128], lred[128], e_sh[128], bvred[128];
    __shared__ int bired[128];
    __shared__ __align__(16) float cat[2 * HH];   // [ctx_raw | hn]
    __shared__ __align__(16) float cat2[2 * HH];  // [context | hn]

    const float* parts = ws + WS_PART + (size_t)b * CHUNKS_PER_B * PART_STRIDE;
    float lraw = 0.0f;
    if (t < 128) {
        const float* p = parts + (size_t)t * PART_STRIDE + 256;
        float mv = p[0]; lraw = p[1];
        marr[t] = mv; mred[t] = mv;
        bvred[t] = p[2]; bired[t] = (int)p[3];
    }
    __syncthreads();
    for (int s = 64; s > 0; s >>= 1) {
        if (t < s) {
            mred[t] = fmaxf(mred[t], mred[t + s]);
            if (bvred[t + s] > bvred[t] ||
                (bvred[t + s] == bvred[t] && bired[t + s] < bired[t])) {
                bvred[t] = bvred[t + s]; bired[t] = bired[t + s];
            }
        }
        __syncthreads();
    }
    const float M = mred[0];
    if (t < 128) {
        float e = __expf(marr[t] - M);
        e_sh[t] = e;
        lred[t] = lraw * e;
    }
    __syncthreads();
    for (int s = 64; s > 0; s >>= 1) {
        if (t < s) lred[t] += lred[t + s];
        __syncthreads();
    }
    const float L = lred[0];
    const int best = bired[0];

    // ctx_raw[t] = (sum_c part_c[t] * e_c) / L
    float acc = 0.0f;
    #pragma unroll 16
    for (int c = 0; c < CHUNKS_PER_B; ++c)
        acc += parts[(size_t)c * PART_STRIDE + t] * e_sh[c];
    const float hnv = ws[WS_HNEW + b * HH + t];
    cat[t] = acc / L;
    cat[HH + t] = hnv;
    cat2[HH + t] = hnv;
    __syncthreads();

    // context = W2 . ctx_raw + b2 : wave-per-4-rows, coalesced row loads
    {
        const float4* v4 = (const float4*)cat;   // 64 float4 of ctx_raw
        const float4 vv = v4[lane];
        #pragma unroll 4
        for (int grp = 0; grp < 16; ++grp) {
            const int rbase = w * 64 + grp * 4;
            float4 w0 = ((const float4*)(W2 + (size_t)(rbase + 0) * HH))[lane];
            float4 w1 = ((const float4*)(W2 + (size_t)(rbase + 1) * HH))[lane];
            float4 w2v = ((const float4*)(W2 + (size_t)(rbase + 2) * HH))[lane];
            float4 w3v = ((const float4*)(W2 + (size_t)(rbase + 3) * HH))[lane];
            float r = merge4(dot4(w0, vv), dot4(w1, vv), dot4(w2v, vv), dot4(w3v, vv), lane);
            if (lane < 4)
                cat2[rbase + lane] = r + b2[rbase + lane];
        }
    }
    __syncthreads();

    // result = W3 . [context, hn] + b3 : rows are 512 wide
    {
        const float4* c4 = (const float4*)cat2;  // 128 float4
        const float4 clo = c4[lane], chi = c4[lane + 64];
        #pragma unroll 4
        for (int grp = 0; grp < 16; ++grp) {
            const int rbase = w * 64 + grp * 4;
            float p[4];
            #pragma unroll
            for (int i = 0; i < 4; ++i) {
                const float4* row = (const float4*)(W3 + (size_t)(rbase + i) * 2 * HH);
                p[i] = dot4(row[lane], clo) + dot4(row[lane + 64], chi);
            }
            float r = merge4(p[0], p[1], p[2], p[3], lane);
            if (lane < 4)
                out[OUT_RESULT + b * HH + rbase + lane] = r + b3[rbase + lane];
        }
    }

    if (t == 0) {
        out[OUT_EV + b] = (float)best;
        out[OUT_MASK + (size_t)b * SS + best] = NEGV;
    }
}

extern "C" void kernel_launch(void* const* d_in, const int* in_sizes, int n_in,
                              void* d_out, int out_size, void* d_ws, size_t ws_size,
                              hipStream_t stream) {
    const float* last_hidden = (const float*)d_in[0];
    const float* dec         = (const float*)d_in[1];
    const float* eo          = (const float*)d_in[2];
    const float* mask        = (const float*)d_in[3];
    const float* gum         = (const float*)d_in[4];
    const float* W1          = (const float*)d_in[5];
    const float* b1          = (const float*)d_in[6];
    const float* W2          = (const float*)d_in[7];
    const float* b2          = (const float*)d_in[8];
    const float* W3          = (const float*)d_in[9];
    const float* b3          = (const float*)d_in[10];
    const float* W_ih        = (const float*)d_in[11];
    const float* W_hh        = (const float*)d_in[12];
    const float* b_ih        = (const float*)d_in[13];
    const float* b_hh        = (const float*)d_in[14];
    float* out = (float*)d_out;
    float* ws  = (float*)d_ws;

    hipLaunchKernelGGL(gates_gemv, dim3(192), dim3(256), 0, stream,
                       dec, last_hidden, W_ih, W_hh, ws);
    hipLaunchKernelGGL(gru_q1, dim3(64), dim3(256), 0, stream,
                       last_hidden, W1, b1, b_ih, b_hh, ws, out);
    hipLaunchKernelGGL(attn_main, dim3(BB * CHUNKS_PER_B), dim3(256), 0, stream,
                       eo, mask, gum, ws, out);
    hipLaunchKernelGGL(finalize, dim3(BB), dim3(256), 0, stream,
                       W2, b2, W3, b3, ws, out);
}